// Round 17
// baseline (174.605 us; speedup 1.0000x reference)
//
#include <hip/hip_runtime.h>

// TriAttention factorized implementation — all-f32 I/O, fp16 MFMA logits.
// dims: B=16, N(v,q,a)=96, D=256, H=128, G=2
// l[v,q,a,g] = sum_h qt[q,h] * (at[a,h]*vt[v,h]*Wg[h,g]); contractions
// factor through pairwise marginals of softmax(l) (p never materialized).
// R17: marginals materialized f16 in BOTH orientations (E*_r rows, E*_t
// transposed) so every k_ctxup staging read is a coalesced row copy —
// R16's o=1/2 staging gathered at 384B lane stride (the last big stall).
// k_mid merge does the vq/va transpose via LDS (stride 98 = conflict-free).

#define B_  16
#define N_  96
#define D_  256
#define H_  128
#define CV  4     // v rows per k_logits workgroup
#define NCH 24    // v-chunks = 96/CV
#define PAD 136   // LDS row stride in f16 elems (272 B, 16B-aligned)

typedef _Float16 f16x8 __attribute__((ext_vector_type(8)));
typedef _Float16 f16x2 __attribute__((ext_vector_type(2)));
typedef __fp16   hf2   __attribute__((ext_vector_type(2)));   // cvt_pkrtz type
typedef float f32x4_t  __attribute__((ext_vector_type(4)));

// ---------------------------------------------------------------------------
// Kernel 1: six projections x@W+b -> [B,96,128].
// p=0: vtg[b,v,g,h] = relu(vt)*Wg[h,g] f16 (both g). p=1,2: relu'd f16.
// p>=3: value projections -> f16 j-octet layout Pp[b][jb][d]{8}.
// grid = 768 (3 WG/CU), 12 tokens/WG.
// ---------------------------------------------------------------------------
__global__ __launch_bounds__(256) void k_proj(
    const float* __restrict__ v, const float* __restrict__ q,
    const float* __restrict__ a,
    const float* __restrict__ Wvt, const float* __restrict__ bvt,
    const float* __restrict__ Wqt, const float* __restrict__ bqt,
    const float* __restrict__ Wat, const float* __restrict__ bat,
    const float* __restrict__ Wvp, const float* __restrict__ bvp,
    const float* __restrict__ Wqp, const float* __restrict__ bqp,
    const float* __restrict__ Wap, const float* __restrict__ bap,
    const float* __restrict__ Wg,
    _Float16* __restrict__ vtg_o, _Float16* __restrict__ qt_o,
    _Float16* __restrict__ at_o,
    _Float16* __restrict__ vpP, _Float16* __restrict__ qpP,
    _Float16* __restrict__ apP)
{
    int wg = blockIdx.x;
    int tc = wg % 8, b = (wg / 8) & 15, p = wg / 128;
    const float* xs_[6] = {v, q, a, v, q, a};
    const float* Ws_[6] = {Wvt, Wqt, Wat, Wvp, Wqp, Wap};
    const float* bs_[6] = {bvt, bqt, bat, bvp, bqp, bap};

    __shared__ __align__(16) float x_l[12 * D_];   // 12 KB

    int tid = threadIdx.x;
    int t0 = tc * 12;
    const float* x = xs_[p] + (size_t)(b * N_ + t0) * D_;
    for (int i = tid; i < 768; i += 256)
        ((float4*)x_l)[i] = ((const float4*)x)[i];
    __syncthreads();

    int d = tid & 127, tg = tid >> 7;
    const float* W = Ws_[p];
    float bias = bs_[p][d];
    float acc[6];
#pragma unroll
    for (int t = 0; t < 6; t++) acc[t] = bias;

    for (int kb = 0; kb < 32; kb++) {
        int k = kb * 8;
        float w0 = W[(k + 0) * H_ + d], w1 = W[(k + 1) * H_ + d];
        float w2 = W[(k + 2) * H_ + d], w3 = W[(k + 3) * H_ + d];
        float w4 = W[(k + 4) * H_ + d], w5 = W[(k + 5) * H_ + d];
        float w6 = W[(k + 6) * H_ + d], w7 = W[(k + 7) * H_ + d];
#pragma unroll
        for (int t = 0; t < 6; t++) {
            int lt = tg * 6 + t;
            float4 xa = *(const float4*)&x_l[lt * D_ + k];
            float4 xb = *(const float4*)&x_l[lt * D_ + k + 4];
            acc[t] += xa.x * w0 + xa.y * w1 + xa.z * w2 + xa.w * w3
                    + xb.x * w4 + xb.y * w5 + xb.z * w6 + xb.w * w7;
        }
    }

    int trow = b * N_ + t0 + tg * 6;
    if (p == 0) {
        float wg0 = Wg[d * 2 + 0], wg1 = Wg[d * 2 + 1];
#pragma unroll
        for (int t = 0; t < 6; t++) {
            float r = fmaxf(acc[t], 0.f);                     // FCNet relu
            _Float16* vg = vtg_o + (size_t)(trow + t) * 2 * H_;
            vg[d]      = (_Float16)(r * wg0);
            vg[H_ + d] = (_Float16)(r * wg1);
        }
    } else if (p < 3) {
        _Float16* o = (p == 1) ? qt_o : at_o;
#pragma unroll
        for (int t = 0; t < 6; t++)
            o[(trow + t) * H_ + d] = (_Float16)fmaxf(acc[t], 0.f);
    } else {
        _Float16* outs[3] = {vpP, qpP, apP};
        _Float16* oP = outs[p - 3] + (size_t)b * 12 * 128 * 8;
#pragma unroll
        for (int t = 0; t < 6; t++) {
            int token = t0 + tg * 6 + t;
            oP[(((token >> 3) * 128) + d) * 8 + (token & 7)] = (_Float16)acc[t];
        }
    }
}

// ---------------------------------------------------------------------------
// Kernel 2 (R15b): logits + exp + marginals, fp16 operands. WG = (b,vc,g),
// grid 768. RAW qt (A) and RAW at staged in LDS once; per v: B frags =
// ds_read(at_l) * vtg8 via v_pk_mul_f16. No clamps on exp (|l| <= ~1).
// E_vq xor-reduction in packed f16; E_qa partials packed-f16 dwords.
// ---------------------------------------------------------------------------
__global__ __launch_bounds__(256) void k_logits(
    const _Float16* __restrict__ vtg, const _Float16* __restrict__ qt,
    const _Float16* __restrict__ at,
    float* __restrict__ Evq_part, float* __restrict__ Eva_part,
    unsigned int* __restrict__ E_qa_part)
{
    int bid = blockIdx.x;
    int g = bid & 1, vc = (bid >> 1) % NCH, b = bid / (2 * NCH);
    int tid = threadIdx.x;

    __shared__ __align__(16) _Float16 qt_l[N_ * PAD];
    __shared__ __align__(16) _Float16 at_l[N_ * PAD];

    const _Float16* qtb = qt + (size_t)b * N_ * H_;
    const _Float16* atb = at + (size_t)b * N_ * H_;

    for (int it = 0; it < 12; it++) {
        int i = tid + it * 256;
        int e = i * 4, t = e >> 7, h = e & 127;
        *(ushort4*)&qt_l[t * PAD + h] = *(const ushort4*)&qtb[e];
        *(ushort4*)&at_l[t * PAD + h] = *(const ushort4*)&atb[e];
    }
    __syncthreads();   // the only barrier

    int wave = tid >> 6, lane = tid & 63, quad = lane >> 4, l15 = lane & 15;
    int qi0 = (wave >> 1) * 3, aj0 = (wave & 1) * 3;

    float eqa[3][3][4];
#pragma unroll
    for (int i = 0; i < 3; i++)
#pragma unroll
        for (int j = 0; j < 3; j++)
#pragma unroll
            for (int r = 0; r < 4; r++) eqa[i][j][r] = 0.f;

    for (int vl = 0; vl < CV; vl++) {
        int vrow = vc * CV + vl;
        const _Float16* vgp = vtg + ((size_t)(b * N_ + vrow) * 2 + g) * H_;

        f32x4_t acc[3][3];
#pragma unroll
        for (int i = 0; i < 3; i++)
#pragma unroll
            for (int j = 0; j < 3; j++)
                acc[i][j] = (f32x4_t){0.f, 0.f, 0.f, 0.f};

#pragma unroll
        for (int ks = 0; ks < 4; ks++) {
            f16x8 v8 = *(const f16x8*)&vgp[ks * 32 + quad * 8];
            f16x8 af[3], bfr[3];
#pragma unroll
            for (int i = 0; i < 3; i++)
                af[i] = *(const f16x8*)&qt_l[((qi0 + i) * 16 + l15) * PAD + ks * 32 + quad * 8];
#pragma unroll
            for (int jt = 0; jt < 3; jt++) {
                f16x8 raw = *(const f16x8*)&at_l[((aj0 + jt) * 16 + l15) * PAD + ks * 32 + quad * 8];
                bfr[jt] = raw * v8;                 // v_pk_mul_f16
            }
#pragma unroll
            for (int i = 0; i < 3; i++)
#pragma unroll
                for (int jt = 0; jt < 3; jt++)
                    acc[i][jt] = __builtin_amdgcn_mfma_f32_16x16x32_f16(af[i], bfr[jt], acc[i][jt], 0, 0, 0);
        }

        // C/D: col(a)=l15, row(q)=quad*4+r  [m89-verified, dtype-independent]
        float s[3][4];
        float c[3];
#pragma unroll
        for (int i = 0; i < 3; i++) {
            s[i][0] = 0.f; s[i][1] = 0.f; s[i][2] = 0.f; s[i][3] = 0.f;
        }
        c[0] = 0.f; c[1] = 0.f; c[2] = 0.f;
#pragma unroll
        for (int i = 0; i < 3; i++)
#pragma unroll
            for (int jt = 0; jt < 3; jt++) {
                float e0 = __expf(acc[i][jt][0]);
                float e1 = __expf(acc[i][jt][1]);
                float e2 = __expf(acc[i][jt][2]);
                float e3 = __expf(acc[i][jt][3]);
                eqa[i][jt][0] += e0; eqa[i][jt][1] += e1;
                eqa[i][jt][2] += e2; eqa[i][jt][3] += e3;
                s[i][0] += e0; s[i][1] += e1; s[i][2] += e2; s[i][3] += e3;
                c[jt] += e0 + e1 + e2 + e3;
            }

        // E_vq: packed-f16 xor-reduce over l15
        float* evqp = Evq_part + ((size_t)bid * CV + vl) * 192 + (wave & 1) * 96;
#pragma unroll
        for (int i = 0; i < 3; i++) {
            union { hf2 h; int w; } u01, u23, o01, o23;
            u01.h = __builtin_amdgcn_cvt_pkrtz(s[i][0], s[i][1]);
            u23.h = __builtin_amdgcn_cvt_pkrtz(s[i][2], s[i][3]);
#pragma unroll
            for (int m = 1; m < 16; m <<= 1) {
                o01.w = __shfl_xor(u01.w, m); u01.h = u01.h + o01.h;
                o23.w = __shfl_xor(u23.w, m); u23.h = u23.h + o23.h;
            }
            if (l15 == 0) {
                int qr = (qi0 + i) * 16 + quad * 4;
                evqp[qr + 0] = (float)u01.h[0];
                evqp[qr + 1] = (float)u01.h[1];
                evqp[qr + 2] = (float)u23.h[0];
                evqp[qr + 3] = (float)u23.h[1];
            }
        }
        float* evap = Eva_part + ((size_t)bid * CV + vl) * 192 + (wave >> 1) * 96;
#pragma unroll
        for (int jt = 0; jt < 3; jt++) {
            float cs = c[jt];
            cs += __shfl_xor(cs, 16);
            cs += __shfl_xor(cs, 32);
            if (lane < 16) evap[(aj0 + jt) * 16 + l15] = cs;
        }
    }

    // E_qa partial flush: packed-f16 dwords, layout [slot][pair(18)][tid]
    unsigned int* Pp = E_qa_part + (size_t)bid * 4608;
#pragma unroll
    for (int i = 0; i < 3; i++)
#pragma unroll
        for (int jt = 0; jt < 3; jt++)
#pragma unroll
            for (int rp = 0; rp < 2; rp++) {
                union { hf2 h; unsigned int w; } u;
                u.h = __builtin_amdgcn_cvt_pkrtz(eqa[i][jt][rp * 2],
                                                 eqa[i][jt][rp * 2 + 1]);
                int pr = (i * 3 + jt) * 2 + rp;
                Pp[pr * 256 + tid] = u.w;
            }
}

// ---------------------------------------------------------------------------
// Kernel 3 (R17): fused reduce + merge + W k-octet transform. grid = 704.
// [0,576): reduce packed-f16 E_qa partial PAIRS -> Eqa_r (f16 rows) +
//          Eqa_t (packed f16 dwords, transposed).
// [576,608): merge marginals -> Evq_r/Evq_t/Eva_r/Eva_t f16 via LDS
//          transpose (row stride 98 = conflict-free) + Zinv.
// [608,704): Wvu/Wqu/Wau -> f16 k-octets.
// ---------------------------------------------------------------------------
__global__ __launch_bounds__(256) void k_mid(
    const unsigned int* __restrict__ E_qa_part,
    const float* __restrict__ Evq_part, const float* __restrict__ Eva_part,
    const float* __restrict__ Wvu, const float* __restrict__ Wqu,
    const float* __restrict__ Wau,
    _Float16* __restrict__ Eqa_r, _Float16* __restrict__ Eqa_t,
    _Float16* __restrict__ Evq_r, _Float16* __restrict__ Evq_t,
    _Float16* __restrict__ Eva_r, _Float16* __restrict__ Eva_t,
    float* __restrict__ Zinv, _Float16* __restrict__ Wp)
{
    __shared__ _Float16 vq_l[96 * 98];   // 18.4 KB
    __shared__ _Float16 va_l[96 * 98];   // 18.4 KB
    __shared__ float red[256];

    int wg = blockIdx.x;
    int tid = threadIdx.x;
    if (wg < 576) {
        int pr = wg % 18, bg = wg / 18;
        int b = bg >> 1, g = bg & 1;
        float s0 = 0.f, s1 = 0.f;
        const unsigned int* Pp = E_qa_part + ((size_t)(b * 2 * NCH + g)) * 4608 + pr * 256 + tid;
#pragma unroll
        for (int vc = 0; vc < NCH; vc++) {
            union { unsigned int w; f16x2 h; } u;
            u.w = Pp[(size_t)vc * 2 * 4608];
            s0 += (float)u.h[0];
            s1 += (float)u.h[1];
        }
        int wave = tid >> 6, lane = tid & 63, quad = lane >> 4, l15 = lane & 15;
        int qi0 = (wave >> 1) * 3, aj0 = (wave & 1) * 3;
        int i = pr / 6, jt = (pr / 2) % 3, rp = pr & 1;
        int qq = (qi0 + i) * 16 + quad * 4 + rp * 2;   // always even
        int aa = (aj0 + jt) * 16 + l15;
        _Float16* Er = Eqa_r + (size_t)bg * 9216;
        Er[qq * 96 + aa]       = (_Float16)s0;
        Er[(qq + 1) * 96 + aa] = (_Float16)s1;
        union { hf2 h; unsigned int w; } t2;
        t2.h = __builtin_amdgcn_cvt_pkrtz(s0, s1);
        *(unsigned int*)((unsigned short*)(Eqa_t + (size_t)bg * 9216) + aa * 96 + qq) = t2.w;
    } else if (wg < 608) {
        int bg = wg - 576;
        int b = bg >> 1, g = bg & 1;
        float z = 0.f;
        for (int i = tid; i < 9216; i += 256) {
            int vrow = i / 96, col = i - vrow * 96;
            int vc = vrow / CV, vl = vrow - vc * CV;
            size_t pb = ((size_t)(b * 2 * NCH + vc * 2 + g) * CV + vl) * 192;
            float s1 = Evq_part[pb + col] + Evq_part[pb + 96 + col];
            vq_l[vrow * 98 + col] = (_Float16)s1;
            z += s1;
            float s2 = Eva_part[pb + col] + Eva_part[pb + 96 + col];
            va_l[vrow * 98 + col] = (_Float16)s2;
        }
        red[tid] = z;
        __syncthreads();
        for (int s = 128; s > 0; s >>= 1) {
            if (tid < s) red[tid] += red[tid + s];
            __syncthreads();
        }
        if (tid == 0) Zinv[bg] = 1.f / fmaxf(red[0], 1e-30f);
        _Float16* vr = Evq_r + (size_t)bg * 9216;
        _Float16* vt_ = Evq_t + (size_t)bg * 9216;
        _Float16* ar = Eva_r + (size_t)bg * 9216;
        _Float16* at_ = Eva_t + (size_t)bg * 9216;
        for (int i = tid; i < 9216; i += 256) {
            int r = i / 96, c = i - r * 96;
            vr[i]  = vq_l[r * 98 + c];
            ar[i]  = va_l[r * 98 + c];
            vt_[i] = vq_l[c * 98 + r];   // stride 98 -> conflict-free
            at_[i] = va_l[c * 98 + r];
        }
    } else {
        int t = wg - 608;                  // 96 blocks: (o, kb)
        int w = t / 32, kb = t % 32;
        const float* Ws[3] = {Wvu, Wqu, Wau};
        const float* W = Ws[w];
        f16x8 o8;
#pragma unroll
        for (int j = 0; j < 8; j++)
            o8[j] = (_Float16)W[(kb * 8 + j) * 256 + tid];   // coalesced in n
        *(f16x8*)&Wp[(((size_t)w * 32 + kb) * 256 + tid) * 8] = o8;
    }
}

// ---------------------------------------------------------------------------
// Kernel 4 (R17): fused ctx+update via fdot2, all-coalesced staging.
// WG = (o, b, tc of 4), grid 1152, both g per WG.
// Staging: pure ushort4 row copies from the f16 E arrays (orientation
// pre-materialized by k_mid). Phase 1 (thread=(g,d)): c = fdot2_j(E, Pp).
// Phase 2 (thread=n): out = x + fdot2_k(c_l, Wp[n-koctets]).
// ---------------------------------------------------------------------------
__global__ __launch_bounds__(256) void k_ctxup(
    const _Float16* __restrict__ Evq_r, const _Float16* __restrict__ Evq_t,
    const _Float16* __restrict__ Eva_r, const _Float16* __restrict__ Eva_t,
    const _Float16* __restrict__ Eqa_r, const _Float16* __restrict__ Eqa_t,
    const _Float16* __restrict__ vpP, const _Float16* __restrict__ qpP,
    const _Float16* __restrict__ apP, const float* __restrict__ Zinv,
    const float* __restrict__ v, const float* __restrict__ q,
    const float* __restrict__ a,
    const _Float16* __restrict__ Wp,
    const float* __restrict__ bvu, const float* __restrict__ bqu,
    const float* __restrict__ bau,
    float* __restrict__ out)
{
    int wg = blockIdx.x;
    int tc = wg % 24, b = (wg / 24) & 15, o = wg / 384;
    int tid = threadIdx.x;
    int t0 = tc * 4;

    __shared__ __align__(16) _Float16 E1l[2][4][96];   // 1.5 KB
    __shared__ __align__(16) _Float16 E2l[2][4][96];   // 1.5 KB
    __shared__ __align__(16) _Float16 c_l[4][256];     // 2 KB

    const _Float16* e1base = (o == 0) ? Evq_r : (o == 1) ? Evq_t : Eva_t;
    const _Float16* e2base = (o == 0) ? Eva_r : (o == 1) ? Eqa_r : Eqa_t;

    for (int i = tid; i < 384; i += 256) {
        int q4 = i % 24, t = (i / 24) % 4, g2 = (i / 96) % 2, arr = i / 192;
        const _Float16* src = (arr ? e2base : e1base)
            + (size_t)(b * 2 + g2) * 9216 + (t0 + t) * 96 + q4 * 4;
        ushort4 val = *(const ushort4*)src;
        _Float16* dst = arr ? &E2l[g2][t][q4 * 4] : &E1l[g2][t][q4 * 4];
        *(ushort4*)dst = val;
    }
    __syncthreads();

    {   // ctx phase: thread = (g2, d); dot over j; coalesced Pp loads
        int d = tid & 127, g2 = tid >> 7;
        const _Float16* P1 = ((o == 0) ? qpP : vpP) + (size_t)b * 12 * 128 * 8;
        const _Float16* P2 = ((o == 2) ? qpP : apP) + (size_t)b * 12 * 128 * 8;
        float accA[4] = {0.f, 0.f, 0.f, 0.f};
        float accB[4] = {0.f, 0.f, 0.f, 0.f};
        for (int jb = 0; jb < 12; jb++) {
            f16x8 p1 = *(const f16x8*)&P1[(jb * 128 + d) * 8];
            f16x8 p2 = *(const f16x8*)&P2[(jb * 128 + d) * 8];
#pragma unroll
            for (int t = 0; t < 4; t++) {
                f16x8 e1 = *(const f16x8*)&E1l[g2][t][jb * 8];
                f16x8 e2 = *(const f16x8*)&E2l[g2][t][jb * 8];
#pragma unroll
                for (int pp = 0; pp < 4; pp++) {
                    accA[t] = __builtin_amdgcn_fdot2(((f16x2*)&e1)[pp], ((f16x2*)&p1)[pp], accA[t], false);
                    accB[t] = __builtin_amdgcn_fdot2(((f16x2*)&e2)[pp], ((f16x2*)&p2)[pp], accB[t], false);
                }
            }
        }
        float zi = Zinv[b * 2 + g2];
        int col = (o == 2) ? (d * 2 + g2) : (g2 * 128 + d);
#pragma unroll
        for (int t = 0; t < 4; t++)
            c_l[t][col] = (_Float16)((accA[t] + accB[t]) * zi);
    }
    __syncthreads();

    // update phase: thread = output column n; dot over k; coalesced Wp loads
    const float* xs_[3] = {v, q, a};
    const float* bs_[3] = {bvu, bqu, bau};
    const float* x = xs_[o] + (size_t)(b * N_ + t0) * 256;
    float bias = bs_[o][tid];
    float accX[4], accY[4];
#pragma unroll
    for (int t = 0; t < 4; t++) {
        accX[t] = bias + x[t * 256 + tid];
        accY[t] = 0.f;
    }

    for (int kb = 0; kb < 32; kb++) {
        f16x8 w8 = *(const f16x8*)&Wp[(((size_t)o * 32 + kb) * 256 + tid) * 8];
#pragma unroll
        for (int t = 0; t < 4; t++) {
            f16x8 c8 = *(const f16x8*)&c_l[t][kb * 8];
            accX[t] = __builtin_amdgcn_fdot2(((f16x2*)&c8)[0], ((f16x2*)&w8)[0], accX[t], false);
            accY[t] = __builtin_amdgcn_fdot2(((f16x2*)&c8)[1], ((f16x2*)&w8)[1], accY[t], false);
            accX[t] = __builtin_amdgcn_fdot2(((f16x2*)&c8)[2], ((f16x2*)&w8)[2], accX[t], false);
            accY[t] = __builtin_amdgcn_fdot2(((f16x2*)&c8)[3], ((f16x2*)&w8)[3], accY[t], false);
        }
    }
    float* ob = out + (size_t)((o * B_ + b) * N_ + t0) * 256;
#pragma unroll
    for (int t = 0; t < 4; t++) ob[t * 256 + tid] = accX[t] + accY[t];
}

// ---------------------------------------------------------------------------
extern "C" void kernel_launch(void* const* d_in, const int* in_sizes, int n_in,
                              void* d_out, int out_size, void* d_ws, size_t ws_size,
                              hipStream_t stream)
{
    const float* v   = (const float*)d_in[0];
    const float* q   = (const float*)d_in[1];
    const float* a   = (const float*)d_in[2];
    const float* Wvt = (const float*)d_in[3];
    const float* bvt = (const float*)d_in[4];
    const float* Wqt = (const float*)d_in[5];
    const float* bqt = (const float*)d_in[6];
    const float* Wat = (const float*)d_in[7];
    const float* bat = (const float*)d_in[8];
    const float* Wg  = (const float*)d_in[9];
    const float* Wvp = (const float*)d_in[10];
    const float* bvp = (const float*)d_in[11];
    const float* Wqp = (const float*)d_in[12];
    const float* bqp = (const float*)d_in[13];
    const float* Wap = (const float*)d_in[14];
    const float* bap = (const float*)d_in[15];
    const float* Wvu = (const float*)d_in[16];
    const float* bvu = (const float*)d_in[17];
    const float* Wqu = (const float*)d_in[18];
    const float* bqu = (const float*)d_in[19];
    const float* Wau = (const float*)d_in[20];
    const float* bau = (const float*)d_in[21];

    char* ws = (char*)d_ws;
    size_t off = 0;
    auto alloc = [&](size_t bytes) {
        char* p = ws + off;
        off += (bytes + 255) & ~(size_t)255;
        return (void*)p;
    };
    _Float16* vtg = (_Float16*)alloc((size_t)B_ * N_ * 2 * H_ * 2);   // 786 KB
    _Float16* qt  = (_Float16*)alloc((size_t)B_ * N_ * H_ * 2);
    _Float16* at  = (_Float16*)alloc((size_t)B_ * N_ * H_ * 2);
    _Float16* vpP = (_Float16*)alloc((size_t)B_ * 12 * 128 * 8 * 2);  // 393 KB
    _Float16* qpP = (_Float16*)alloc((size_t)B_ * 12 * 128 * 8 * 2);
    _Float16* apP = (_Float16*)alloc((size_t)B_ * 12 * 128 * 8 * 2);
    _Float16* Eqa_r = (_Float16*)alloc((size_t)B_ * 2 * 9216 * 2);    // 590 KB ea
    _Float16* Eqa_t = (_Float16*)alloc((size_t)B_ * 2 * 9216 * 2);
    _Float16* Evq_r = (_Float16*)alloc((size_t)B_ * 2 * 9216 * 2);
    _Float16* Evq_t = (_Float16*)alloc((size_t)B_ * 2 * 9216 * 2);
    _Float16* Eva_r = (_Float16*)alloc((size_t)B_ * 2 * 9216 * 2);
    _Float16* Eva_t = (_Float16*)alloc((size_t)B_ * 2 * 9216 * 2);
    float* Zinv = (float*)alloc(256);
    float* Evq_part = (float*)alloc((size_t)768 * CV * 192 * 4);   // 2.36 MB
    float* Eva_part = (float*)alloc((size_t)768 * CV * 192 * 4);   // 2.36 MB
    unsigned int* E_qa_part =
        (unsigned int*)alloc((size_t)B_ * NCH * 2 * 4608 * 4);     // 14.2 MB
    _Float16* Wp = (_Float16*)alloc((size_t)3 * 32 * 256 * 8 * 2); // 384 KB
    // total ~25 MB

    k_proj<<<768, 256, 0, stream>>>(v, q, a, Wvt, bvt, Wqt, bqt, Wat, bat,
                                    Wvp, bvp, Wqp, bqp, Wap, bap, Wg,
                                    vtg, qt, at, vpP, qpP, apP);
    k_logits<<<B_ * NCH * 2, 256, 0, stream>>>(vtg, qt, at,
                                               Evq_part, Eva_part, E_qa_part);
    k_mid<<<704, 256, 0, stream>>>(E_qa_part, Evq_part, Eva_part,
                                   Wvu, Wqu, Wau,
                                   Eqa_r, Eqa_t, Evq_r, Evq_t, Eva_r, Eva_t,
                                   Zinv, Wp);
    k_ctxup<<<1152, 256, 0, stream>>>(Evq_r, Evq_t, Eva_r, Eva_t, Eqa_r, Eqa_t,
                                      vpP, qpP, apP, Zinv,
                                      v, q, a, Wp, bvu, bqu, bau,
                                      (float*)d_out);
}

// Round 18
// 172.012 us; speedup vs baseline: 1.0151x; 1.0151x over previous
//
#include <hip/hip_runtime.h>

// TriAttention factorized implementation — all-f32 I/O, fp16 MFMA logits.
// dims: B=16, N(v,q,a)=96, D=256, H=128, G=2
// l[v,q,a,g] = sum_h qt[q,h] * (at[a,h]*vt[v,h]*Wg[h,g]); contractions
// factor through pairwise marginals of softmax(l) (p never materialized).
// R18: revert to R16 (measured best, 172.5 us); + log2e folded into vtg so
// exp is a bare v_exp_f32 (saves 144 VALU/thread in k_logits); + W k-octet
// transform moved from k_mid to k_proj (off the critical path).

#define B_  16
#define N_  96
#define D_  256
#define H_  128
#define CV  4     // v rows per k_logits workgroup
#define NCH 24    // v-chunks = 96/CV
#define PAD 136   // LDS row stride in f16 elems (272 B, 16B-aligned)

typedef _Float16 f16x8 __attribute__((ext_vector_type(8)));
typedef _Float16 f16x2 __attribute__((ext_vector_type(2)));
typedef __fp16   hf2   __attribute__((ext_vector_type(2)));   // cvt_pkrtz type
typedef float f32x4_t  __attribute__((ext_vector_type(4)));

// ---------------------------------------------------------------------------
// Kernel 1: six projections x@W+b -> [B,96,128]  (blocks [0,768))
// p=0: vtg[b,v,g,h] = relu(vt)*Wg[h,g]*log2e f16. p=1,2: relu'd f16.
// p>=3: value projections -> f16 j-octet layout Pp[b][jb][d]{8}.
// Blocks [768,864): Wvu/Wqu/Wau f32[k][n] -> f16 Wp k-octets (independent
// work, overlaps k_logits instead of delaying k_ctxup via k_mid).
// ---------------------------------------------------------------------------
__global__ __launch_bounds__(256) void k_proj(
    const float* __restrict__ v, const float* __restrict__ q,
    const float* __restrict__ a,
    const float* __restrict__ Wvt, const float* __restrict__ bvt,
    const float* __restrict__ Wqt, const float* __restrict__ bqt,
    const float* __restrict__ Wat, const float* __restrict__ bat,
    const float* __restrict__ Wvp, const float* __restrict__ bvp,
    const float* __restrict__ Wqp, const float* __restrict__ bqp,
    const float* __restrict__ Wap, const float* __restrict__ bap,
    const float* __restrict__ Wg,
    const float* __restrict__ Wvu, const float* __restrict__ Wqu,
    const float* __restrict__ Wau,
    _Float16* __restrict__ vtg_o, _Float16* __restrict__ qt_o,
    _Float16* __restrict__ at_o,
    _Float16* __restrict__ vpP, _Float16* __restrict__ qpP,
    _Float16* __restrict__ apP, _Float16* __restrict__ Wp)
{
    int wg = blockIdx.x;
    int tid = threadIdx.x;
    if (wg >= 768) {                       // W k-octet transform
        int t = wg - 768, w = t / 32, kb = t % 32;
        const float* Ws[3] = {Wvu, Wqu, Wau};
        const float* W = Ws[w];
        f16x8 o8;
#pragma unroll
        for (int j = 0; j < 8; j++)
            o8[j] = (_Float16)W[(kb * 8 + j) * 256 + tid];   // coalesced in n
        *(f16x8*)&Wp[(((size_t)w * 32 + kb) * 256 + tid) * 8] = o8;
        return;
    }

    int tc = wg % 8, b = (wg / 8) & 15, p = wg / 128;
    const float* xs_[6] = {v, q, a, v, q, a};
    const float* Ws_[6] = {Wvt, Wqt, Wat, Wvp, Wqp, Wap};
    const float* bs_[6] = {bvt, bqt, bat, bvp, bqp, bap};

    __shared__ __align__(16) float x_l[12 * D_];   // 12 KB

    int t0 = tc * 12;
    const float* x = xs_[p] + (size_t)(b * N_ + t0) * D_;
    for (int i = tid; i < 768; i += 256)
        ((float4*)x_l)[i] = ((const float4*)x)[i];
    __syncthreads();

    int d = tid & 127, tg = tid >> 7;
    const float* W = Ws_[p];
    float bias = bs_[p][d];
    float acc[6];
#pragma unroll
    for (int t = 0; t < 6; t++) acc[t] = bias;

    for (int kb = 0; kb < 32; kb++) {
        int k = kb * 8;
        float w0 = W[(k + 0) * H_ + d], w1 = W[(k + 1) * H_ + d];
        float w2 = W[(k + 2) * H_ + d], w3 = W[(k + 3) * H_ + d];
        float w4 = W[(k + 4) * H_ + d], w5 = W[(k + 5) * H_ + d];
        float w6 = W[(k + 6) * H_ + d], w7 = W[(k + 7) * H_ + d];
#pragma unroll
        for (int t = 0; t < 6; t++) {
            int lt = tg * 6 + t;
            float4 xa = *(const float4*)&x_l[lt * D_ + k];
            float4 xb = *(const float4*)&x_l[lt * D_ + k + 4];
            acc[t] += xa.x * w0 + xa.y * w1 + xa.z * w2 + xa.w * w3
                    + xb.x * w4 + xb.y * w5 + xb.z * w6 + xb.w * w7;
        }
    }

    int trow = b * N_ + t0 + tg * 6;
    if (p == 0) {
        const float LOG2E = 1.4426950408889634f;   // folded: exp -> v_exp_f32
        float wg0 = Wg[d * 2 + 0] * LOG2E, wg1 = Wg[d * 2 + 1] * LOG2E;
#pragma unroll
        for (int t = 0; t < 6; t++) {
            float r = fmaxf(acc[t], 0.f);                     // FCNet relu
            _Float16* vg = vtg_o + (size_t)(trow + t) * 2 * H_;
            vg[d]      = (_Float16)(r * wg0);
            vg[H_ + d] = (_Float16)(r * wg1);
        }
    } else if (p < 3) {
        _Float16* o = (p == 1) ? qt_o : at_o;
#pragma unroll
        for (int t = 0; t < 6; t++)
            o[(trow + t) * H_ + d] = (_Float16)fmaxf(acc[t], 0.f);
    } else {
        _Float16* outs[3] = {vpP, qpP, apP};
        _Float16* oP = outs[p - 3] + (size_t)b * 12 * 128 * 8;
#pragma unroll
        for (int t = 0; t < 6; t++) {
            int token = t0 + tg * 6 + t;
            oP[(((token >> 3) * 128) + d) * 8 + (token & 7)] = (_Float16)acc[t];
        }
    }
}

// ---------------------------------------------------------------------------
// Kernel 2: logits + exp + marginals, fp16 operands. WG = (b,vc,g), grid 768.
// RAW qt (A) and RAW at staged in LDS once; per v: B frags = ds_read(at_l) *
// vtg8 (log2e pre-folded) via v_pk_mul_f16; exp = bare v_exp_f32.
// E_vq xor-reduction packed f16; E_qa partials packed-f16 dwords.
// ---------------------------------------------------------------------------
__global__ __launch_bounds__(256) void k_logits(
    const _Float16* __restrict__ vtg, const _Float16* __restrict__ qt,
    const _Float16* __restrict__ at,
    float* __restrict__ Evq_part, float* __restrict__ Eva_part,
    unsigned int* __restrict__ E_qa_part)
{
    int bid = blockIdx.x;
    int g = bid & 1, vc = (bid >> 1) % NCH, b = bid / (2 * NCH);
    int tid = threadIdx.x;

    __shared__ __align__(16) _Float16 qt_l[N_ * PAD];
    __shared__ __align__(16) _Float16 at_l[N_ * PAD];

    const _Float16* qtb = qt + (size_t)b * N_ * H_;
    const _Float16* atb = at + (size_t)b * N_ * H_;

    for (int it = 0; it < 12; it++) {
        int i = tid + it * 256;
        int e = i * 4, t = e >> 7, h = e & 127;
        *(ushort4*)&qt_l[t * PAD + h] = *(const ushort4*)&qtb[e];
        *(ushort4*)&at_l[t * PAD + h] = *(const ushort4*)&atb[e];
    }
    __syncthreads();   // the only barrier

    int wave = tid >> 6, lane = tid & 63, quad = lane >> 4, l15 = lane & 15;
    int qi0 = (wave >> 1) * 3, aj0 = (wave & 1) * 3;

    float eqa[3][3][4];
#pragma unroll
    for (int i = 0; i < 3; i++)
#pragma unroll
        for (int j = 0; j < 3; j++)
#pragma unroll
            for (int r = 0; r < 4; r++) eqa[i][j][r] = 0.f;

    for (int vl = 0; vl < CV; vl++) {
        int vrow = vc * CV + vl;
        const _Float16* vgp = vtg + ((size_t)(b * N_ + vrow) * 2 + g) * H_;

        f32x4_t acc[3][3];
#pragma unroll
        for (int i = 0; i < 3; i++)
#pragma unroll
            for (int j = 0; j < 3; j++)
                acc[i][j] = (f32x4_t){0.f, 0.f, 0.f, 0.f};

#pragma unroll
        for (int ks = 0; ks < 4; ks++) {
            f16x8 v8 = *(const f16x8*)&vgp[ks * 32 + quad * 8];
            f16x8 af[3], bfr[3];
#pragma unroll
            for (int i = 0; i < 3; i++)
                af[i] = *(const f16x8*)&qt_l[((qi0 + i) * 16 + l15) * PAD + ks * 32 + quad * 8];
#pragma unroll
            for (int jt = 0; jt < 3; jt++) {
                f16x8 raw = *(const f16x8*)&at_l[((aj0 + jt) * 16 + l15) * PAD + ks * 32 + quad * 8];
                bfr[jt] = raw * v8;                 // v_pk_mul_f16
            }
#pragma unroll
            for (int i = 0; i < 3; i++)
#pragma unroll
                for (int jt = 0; jt < 3; jt++)
                    acc[i][jt] = __builtin_amdgcn_mfma_f32_16x16x32_f16(af[i], bfr[jt], acc[i][jt], 0, 0, 0);
        }

        // C/D: col(a)=l15, row(q)=quad*4+r  [m89-verified, dtype-independent]
        float s[3][4];
        float c[3];
#pragma unroll
        for (int i = 0; i < 3; i++) {
            s[i][0] = 0.f; s[i][1] = 0.f; s[i][2] = 0.f; s[i][3] = 0.f;
        }
        c[0] = 0.f; c[1] = 0.f; c[2] = 0.f;
#pragma unroll
        for (int i = 0; i < 3; i++)
#pragma unroll
            for (int jt = 0; jt < 3; jt++) {
                // acc already holds l*log2e (folded in vtg): bare 2^x
                float e0 = __builtin_amdgcn_exp2f(acc[i][jt][0]);
                float e1 = __builtin_amdgcn_exp2f(acc[i][jt][1]);
                float e2 = __builtin_amdgcn_exp2f(acc[i][jt][2]);
                float e3 = __builtin_amdgcn_exp2f(acc[i][jt][3]);
                eqa[i][jt][0] += e0; eqa[i][jt][1] += e1;
                eqa[i][jt][2] += e2; eqa[i][jt][3] += e3;
                s[i][0] += e0; s[i][1] += e1; s[i][2] += e2; s[i][3] += e3;
                c[jt] += e0 + e1 + e2 + e3;
            }

        // E_vq: packed-f16 xor-reduce over l15
        float* evqp = Evq_part + ((size_t)bid * CV + vl) * 192 + (wave & 1) * 96;
#pragma unroll
        for (int i = 0; i < 3; i++) {
            union { hf2 h; int w; } u01, u23, o01, o23;
            u01.h = __builtin_amdgcn_cvt_pkrtz(s[i][0], s[i][1]);
            u23.h = __builtin_amdgcn_cvt_pkrtz(s[i][2], s[i][3]);
#pragma unroll
            for (int m = 1; m < 16; m <<= 1) {
                o01.w = __shfl_xor(u01.w, m); u01.h = u01.h + o01.h;
                o23.w = __shfl_xor(u23.w, m); u23.h = u23.h + o23.h;
            }
            if (l15 == 0) {
                int qr = (qi0 + i) * 16 + quad * 4;
                evqp[qr + 0] = (float)u01.h[0];
                evqp[qr + 1] = (float)u01.h[1];
                evqp[qr + 2] = (float)u23.h[0];
                evqp[qr + 3] = (float)u23.h[1];
            }
        }
        float* evap = Eva_part + ((size_t)bid * CV + vl) * 192 + (wave >> 1) * 96;
#pragma unroll
        for (int jt = 0; jt < 3; jt++) {
            float cs = c[jt];
            cs += __shfl_xor(cs, 16);
            cs += __shfl_xor(cs, 32);
            if (lane < 16) evap[(aj0 + jt) * 16 + l15] = cs;
        }
    }

    // E_qa partial flush: packed-f16 dwords, layout [slot][pair(18)][tid]
    unsigned int* Pp = E_qa_part + (size_t)bid * 4608;
#pragma unroll
    for (int i = 0; i < 3; i++)
#pragma unroll
        for (int jt = 0; jt < 3; jt++)
#pragma unroll
            for (int rp = 0; rp < 2; rp++) {
                union { hf2 h; unsigned int w; } u;
                u.h = __builtin_amdgcn_cvt_pkrtz(eqa[i][jt][rp * 2],
                                                 eqa[i][jt][rp * 2 + 1]);
                int pr = (i * 3 + jt) * 2 + rp;
                Pp[pr * 256 + tid] = u.w;
            }
}

// ---------------------------------------------------------------------------
// Kernel 3: fused reduce + merge. grid = 608.
// [0,576): reduce packed-f16 E_qa partial PAIRS over NCH vc slots.
// [576,608): merge marginals + Zinv.
// ---------------------------------------------------------------------------
__global__ __launch_bounds__(256) void k_mid(
    const unsigned int* __restrict__ E_qa_part,
    const float* __restrict__ Evq_part, const float* __restrict__ Eva_part,
    float* __restrict__ E_qa, float* __restrict__ E_vq,
    float* __restrict__ E_va, float* __restrict__ Zinv)
{
    int wg = blockIdx.x;
    int tid = threadIdx.x;
    if (wg < 576) {
        int pr = wg % 18, bg = wg / 18;
        int b = bg >> 1, g = bg & 1;
        float s0 = 0.f, s1 = 0.f;
        const unsigned int* Pp = E_qa_part + ((size_t)(b * 2 * NCH + g)) * 4608 + pr * 256 + tid;
#pragma unroll
        for (int vc = 0; vc < NCH; vc++) {
            union { unsigned int w; f16x2 h; } u;
            u.w = Pp[(size_t)vc * 2 * 4608];
            s0 += (float)u.h[0];
            s1 += (float)u.h[1];
        }
        int wave = tid >> 6, lane = tid & 63, quad = lane >> 4, l15 = lane & 15;
        int qi0 = (wave >> 1) * 3, aj0 = (wave & 1) * 3;
        int i = pr / 6, jt = (pr / 2) % 3, rp = pr & 1;
        int qq = (qi0 + i) * 16 + quad * 4 + rp * 2;
        int aa = (aj0 + jt) * 16 + l15;
        float* Eq = E_qa + (size_t)bg * 9216;
        Eq[qq * 96 + aa]       = s0;
        Eq[(qq + 1) * 96 + aa] = s1;
    } else {
        int bg = wg - 576;
        int b = bg >> 1, g = bg & 1;
        float z = 0.f;
        for (int i = tid; i < 9216; i += 256) {
            int vrow = i / 96, col = i - vrow * 96;
            int vc = vrow / CV, vl = vrow - vc * CV;
            size_t pb = ((size_t)(b * 2 * NCH + vc * 2 + g) * CV + vl) * 192;
            float s1 = Evq_part[pb + col] + Evq_part[pb + 96 + col];
            E_vq[(b * 2 + g) * 9216 + i] = s1;
            z += s1;
            float s2 = Eva_part[pb + col] + Eva_part[pb + 96 + col];
            E_va[(b * 2 + g) * 9216 + i] = s2;
        }
        __shared__ float red[256];
        red[tid] = z;
        __syncthreads();
        for (int s = 128; s > 0; s >>= 1) {
            if (tid < s) red[tid] += red[tid + s];
            __syncthreads();
        }
        if (tid == 0) Zinv[b * 2 + g] = 1.f / fmaxf(red[0], 1e-30f);
    }
}

// ---------------------------------------------------------------------------
// Kernel 4: fused ctx+update via fdot2, coalesced octet layouts (R16).
// WG = (o, b, tc of 4), grid 1152, both g per WG.
// ---------------------------------------------------------------------------
__global__ __launch_bounds__(256) void k_ctxup(
    const float* __restrict__ E_vq, const float* __restrict__ E_va,
    const float* __restrict__ E_qa,
    const _Float16* __restrict__ vpP, const _Float16* __restrict__ qpP,
    const _Float16* __restrict__ apP, const float* __restrict__ Zinv,
    const float* __restrict__ v, const float* __restrict__ q,
    const float* __restrict__ a,
    const _Float16* __restrict__ Wp,
    const float* __restrict__ bvu, const float* __restrict__ bqu,
    const float* __restrict__ bau,
    float* __restrict__ out)
{
    int wg = blockIdx.x;
    int tc = wg % 24, b = (wg / 24) & 15, o = wg / 384;
    int tid = threadIdx.x;
    int t0 = tc * 4;

    __shared__ __align__(16) _Float16 E1l[2][4][96];   // 1.5 KB
    __shared__ __align__(16) _Float16 E2l[2][4][96];   // 1.5 KB
    __shared__ __align__(16) _Float16 c_l[4][256];     // 2 KB

    for (int i = tid; i < 768; i += 256) {
        int g2 = i / 384, rem = i - g2 * 384;
        int t = rem / 96, j = rem - t * 96;
        const float* Evq = E_vq + (b * 2 + g2) * 9216;
        const float* Eva = E_va + (b * 2 + g2) * 9216;
        const float* Eqa = E_qa + (b * 2 + g2) * 9216;
        float e1, e2;
        if (o == 0)      { e1 = Evq[(t0 + t) * 96 + j]; e2 = Eva[(t0 + t) * 96 + j]; }
        else if (o == 1) { e1 = Evq[j * 96 + t0 + t];   e2 = Eqa[(t0 + t) * 96 + j]; }
        else             { e1 = Eva[j * 96 + t0 + t];   e2 = Eqa[j * 96 + t0 + t]; }
        E1l[g2][t][j] = (_Float16)e1;
        E2l[g2][t][j] = (_Float16)e2;
    }
    __syncthreads();

    {   // ctx phase: thread = (g2, d); dot over j; coalesced Pp loads
        int d = tid & 127, g2 = tid >> 7;
        const _Float16* P1 = ((o == 0) ? qpP : vpP) + (size_t)b * 12 * 128 * 8;
        const _Float16* P2 = ((o == 2) ? qpP : apP) + (size_t)b * 12 * 128 * 8;
        float accA[4] = {0.f, 0.f, 0.f, 0.f};
        float accB[4] = {0.f, 0.f, 0.f, 0.f};
        for (int jb = 0; jb < 12; jb++) {
            f16x8 p1 = *(const f16x8*)&P1[(jb * 128 + d) * 8];
            f16x8 p2 = *(const f16x8*)&P2[(jb * 128 + d) * 8];
#pragma unroll
            for (int t = 0; t < 4; t++) {
                f16x8 e1 = *(const f16x8*)&E1l[g2][t][jb * 8];
                f16x8 e2 = *(const f16x8*)&E2l[g2][t][jb * 8];
#pragma unroll
                for (int pp = 0; pp < 4; pp++) {
                    accA[t] = __builtin_amdgcn_fdot2(((f16x2*)&e1)[pp], ((f16x2*)&p1)[pp], accA[t], false);
                    accB[t] = __builtin_amdgcn_fdot2(((f16x2*)&e2)[pp], ((f16x2*)&p2)[pp], accB[t], false);
                }
            }
        }
        float zi = Zinv[b * 2 + g2];
        int col = (o == 2) ? (d * 2 + g2) : (g2 * 128 + d);
#pragma unroll
        for (int t = 0; t < 4; t++)
            c_l[t][col] = (_Float16)((accA[t] + accB[t]) * zi);
    }
    __syncthreads();

    // update phase: thread = output column n; dot over k; coalesced Wp loads
    const float* xs_[3] = {v, q, a};
    const float* bs_[3] = {bvu, bqu, bau};
    const float* x = xs_[o] + (size_t)(b * N_ + t0) * 256;
    float bias = bs_[o][tid];
    float accX[4], accY[4];
#pragma unroll
    for (int t = 0; t < 4; t++) {
        accX[t] = bias + x[t * 256 + tid];
        accY[t] = 0.f;
    }

    for (int kb = 0; kb < 32; kb++) {
        f16x8 w8 = *(const f16x8*)&Wp[(((size_t)o * 32 + kb) * 256 + tid) * 8];
#pragma unroll
        for (int t = 0; t < 4; t++) {
            f16x8 c8 = *(const f16x8*)&c_l[t][kb * 8];
            accX[t] = __builtin_amdgcn_fdot2(((f16x2*)&c8)[0], ((f16x2*)&w8)[0], accX[t], false);
            accY[t] = __builtin_amdgcn_fdot2(((f16x2*)&c8)[1], ((f16x2*)&w8)[1], accY[t], false);
            accX[t] = __builtin_amdgcn_fdot2(((f16x2*)&c8)[2], ((f16x2*)&w8)[2], accX[t], false);
            accY[t] = __builtin_amdgcn_fdot2(((f16x2*)&c8)[3], ((f16x2*)&w8)[3], accY[t], false);
        }
    }
    float* ob = out + (size_t)((o * B_ + b) * N_ + t0) * 256;
#pragma unroll
    for (int t = 0; t < 4; t++) ob[t * 256 + tid] = accX[t] + accY[t];
}

// ---------------------------------------------------------------------------
extern "C" void kernel_launch(void* const* d_in, const int* in_sizes, int n_in,
                              void* d_out, int out_size, void* d_ws, size_t ws_size,
                              hipStream_t stream)
{
    const float* v   = (const float*)d_in[0];
    const float* q   = (const float*)d_in[1];
    const float* a   = (const float*)d_in[2];
    const float* Wvt = (const float*)d_in[3];
    const float* bvt = (const float*)d_in[4];
    const float* Wqt = (const float*)d_in[5];
    const float* bqt = (const float*)d_in[6];
    const float* Wat = (const float*)d_in[7];
    const float* bat = (const float*)d_in[8];
    const float* Wg  = (const float*)d_in[9];
    const float* Wvp = (const float*)d_in[10];
    const float* bvp = (const float*)d_in[11];
    const float* Wqp = (const float*)d_in[12];
    const float* bqp = (const float*)d_in[13];
    const float* Wap = (const float*)d_in[14];
    const float* bap = (const float*)d_in[15];
    const float* Wvu = (const float*)d_in[16];
    const float* bvu = (const float*)d_in[17];
    const float* Wqu = (const float*)d_in[18];
    const float* bqu = (const float*)d_in[19];
    const float* Wau = (const float*)d_in[20];
    const float* bau = (const float*)d_in[21];

    char* ws = (char*)d_ws;
    size_t off = 0;
    auto alloc = [&](size_t bytes) {
        char* p = ws + off;
        off += (bytes + 255) & ~(size_t)255;
        return (void*)p;
    };
    _Float16* vtg = (_Float16*)alloc((size_t)B_ * N_ * 2 * H_ * 2);   // 786 KB
    _Float16* qt  = (_Float16*)alloc((size_t)B_ * N_ * H_ * 2);
    _Float16* at  = (_Float16*)alloc((size_t)B_ * N_ * H_ * 2);
    _Float16* vpP = (_Float16*)alloc((size_t)B_ * 12 * 128 * 8 * 2);  // 393 KB
    _Float16* qpP = (_Float16*)alloc((size_t)B_ * 12 * 128 * 8 * 2);
    _Float16* apP = (_Float16*)alloc((size_t)B_ * 12 * 128 * 8 * 2);
    float* E_vq = (float*)alloc((size_t)B_ * 2 * 9216 * 4);
    float* E_va = (float*)alloc((size_t)B_ * 2 * 9216 * 4);
    float* E_qa = (float*)alloc((size_t)B_ * 2 * 9216 * 4);
    float* Zinv = (float*)alloc(256);
    float* Evq_part = (float*)alloc((size_t)768 * CV * 192 * 4);   // 2.36 MB
    float* Eva_part = (float*)alloc((size_t)768 * CV * 192 * 4);   // 2.36 MB
    unsigned int* E_qa_part =
        (unsigned int*)alloc((size_t)B_ * NCH * 2 * 4608 * 4);     // 14.2 MB
    _Float16* Wp = (_Float16*)alloc((size_t)3 * 32 * 256 * 8 * 2); // 384 KB
    // total ~25 MB

    k_proj<<<864, 256, 0, stream>>>(v, q, a, Wvt, bvt, Wqt, bqt, Wat, bat,
                                    Wvp, bvp, Wqp, bqp, Wap, bap, Wg,
                                    Wvu, Wqu, Wau,
                                    vtg, qt, at, vpP, qpP, apP, Wp);
    k_logits<<<B_ * NCH * 2, 256, 0, stream>>>(vtg, qt, at,
                                               Evq_part, Eva_part, E_qa_part);
    k_mid<<<608, 256, 0, stream>>>(E_qa_part, Evq_part, Eva_part,
                                   E_qa, E_vq, E_va, Zinv);
    k_ctxup<<<1152, 256, 0, stream>>>(E_vq, E_va, E_qa, vpP, qpP, apP, Zinv,
                                      v, q, a, Wp, bvu, bqu, bau,
                                      (float*)d_out);
}